// Round 1
// baseline (211.978 us; speedup 1.0000x reference)
//
#include <hip/hip_runtime.h>

// LightningIndexer: out[b,q,k] = sum_h w_h * relu( (xWq^T+bq)[b,q,h,:] . (xWk^T+bk)[b,k,h,:] )
// B=2, S=4096, Dmodel=1024, H=4, HD=64.
// R5: (1) operand-swapped MFMA in both GEMMs -> reg axis = k/n = contiguous,
//     float4 nontemporal stores for the 134MB score output, bf16x4 for Q/K;
//     (2) 2-phase double-buffered async staging (issue next tile before
//     compute, one drain+barrier per phase); (3) x pre-converted to bf16
//     (xb parked in d_out scratch; dead before k_scores overwrites), k_proj
//     A-side now async16+swizzle, BM=64/BN=256 z-split.

typedef __bf16 bf16;
typedef __bf16 bf16x4 __attribute__((ext_vector_type(4)));
typedef __bf16 bf16x8 __attribute__((ext_vector_type(8)));
typedef float f32x4 __attribute__((ext_vector_type(4)));

#define SEQ 4096
#define DMODEL 1024
#define NPROJ 256       // NHEAD*HDIM
#define MTOT 8192       // NB*SEQ

// async global->LDS, 16B per lane; LDS dest = wave-uniform base + lane*16
__device__ __forceinline__ void async16(const void* g, void* l) {
  __builtin_amdgcn_global_load_lds(
      (const __attribute__((address_space(1))) void*)g,
      (__attribute__((address_space(3))) void*)l, 16, 0, 0);
}

// ---------------- K0: convert x, Wq, Wk fp32 -> bf16 ----------------
// blocks 0..2047: x (2,097,152 float4; 4/thread). blocks 2048..2175: weights.
__global__ __launch_bounds__(256) void k_convert(const float* __restrict__ x,
                                                 const float* __restrict__ wq,
                                                 const float* __restrict__ wk,
                                                 bf16* __restrict__ xb,
                                                 bf16* __restrict__ wqb,
                                                 bf16* __restrict__ wkb) {
  const int b = blockIdx.x, t = threadIdx.x;
  if (b < 2048) {
    int i = b * 256 + t;
#pragma unroll
    for (int r = 0; r < 4; r++) {
      float4 v = ((const float4*)x)[i + r * 524288];
      bf16x4 o = {(bf16)v.x, (bf16)v.y, (bf16)v.z, (bf16)v.w};
      ((bf16x4*)xb)[i + r * 524288] = o;
    }
  } else {
    int i = (b - 2048) * 256 + t;
#pragma unroll
    for (int r = 0; r < 2; r++) {
      float4 a = ((const float4*)wq)[i + r * 32768];
      bf16x4 oa = {(bf16)a.x, (bf16)a.y, (bf16)a.z, (bf16)a.w};
      ((bf16x4*)wqb)[i + r * 32768] = oa;
      float4 c = ((const float4*)wk)[i + r * 32768];
      bf16x4 oc = {(bf16)c.x, (bf16)c.y, (bf16)c.z, (bf16)c.w};
      ((bf16x4*)wkb)[i + r * 32768] = oc;
    }
  }
}

// ---------------- K1: projection GEMM (swapped, 2-phase) ----------------
// out[m,n] = sum_d x[m,d]*W[n,d] + bias[n], bf16 out.
// BM=64, BN=256, BK=64. grid (128 mtiles, 2 z) = 256 blocks (1/CU).
// MFMA A=W rows (n), B=x rows (m) -> D reg axis = n -> bf16x4 stores.
__global__ __launch_bounds__(256, 1) void k_proj(
    const bf16* __restrict__ xb, const bf16* __restrict__ wqb,
    const bf16* __restrict__ wkb, const float* __restrict__ qbias,
    const float* __restrict__ kbias, bf16* __restrict__ Qb,
    bf16* __restrict__ Kb) {
  __shared__ __align__(16) bf16 As[2][64 * 64];    // x tile,  8 KB each
  __shared__ __align__(16) bf16 Bs[2][256 * 64];   // W tile, 32 KB each
  const int t = threadIdx.x;
  const int lane = t & 63, w = t >> 6;
  const int m16 = lane & 15, q = lane >> 4;
  const int m0 = blockIdx.x * 64;
  const int z = blockIdx.y;
  const bf16* __restrict__ W = z ? wkb : wqb;

  f32x4 acc[4][4];
#pragma unroll
  for (int nt = 0; nt < 4; nt++)
#pragma unroll
    for (int mt = 0; mt < 4; mt++) acc[nt][mt] = {0.f, 0.f, 0.f, 0.f};

  auto stage = [&](int buf, int kt) {
    // A: 64 rows x 64 cols bf16 = 8 KB = 8 calls (2/wave), 8 rows/call
#pragma unroll
    for (int p = 0; p < 2; p++) {
      int g = w * 2 + p;
      int r = g * 8 + (lane >> 3);
      int c = (lane & 7) ^ (r & 7);           // XOR chunk swizzle (src side)
      async16(xb + (size_t)(m0 + r) * DMODEL + kt * 64 + c * 8,
              As[buf] + g * 512);
    }
    // B: 256 rows x 64 cols = 32 KB = 32 calls (8/wave)
#pragma unroll
    for (int p = 0; p < 8; p++) {
      int g = w * 8 + p;
      int r = g * 8 + (lane >> 3);
      int c = (lane & 7) ^ (r & 7);
      async16(W + (size_t)r * DMODEL + kt * 64 + c * 8, Bs[buf] + g * 512);
    }
  };

  stage(0, 0);
  __builtin_amdgcn_s_waitcnt(0);
  __syncthreads();

  for (int kt = 0; kt < 16; kt++) {
    if (kt < 15) stage((kt + 1) & 1, kt + 1);   // issue next tile first
    const bf16* As_ = As[kt & 1];
    const bf16* Bs_ = Bs[kt & 1];
#pragma unroll
    for (int s = 0; s < 2; s++) {
      bf16x8 af[4], bx[4];
#pragma unroll
      for (int nt = 0; nt < 4; nt++) {
        int n = w * 64 + nt * 16 + m16;
        int cc = (s * 4 + q) ^ (n & 7);
        af[nt] = *(const bf16x8*)(Bs_ + n * 64 + cc * 8);
      }
#pragma unroll
      for (int mt = 0; mt < 4; mt++) {
        int m = mt * 16 + m16;
        int cc = (s * 4 + q) ^ (m & 7);
        bx[mt] = *(const bf16x8*)(As_ + m * 64 + cc * 8);
      }
#pragma unroll
      for (int nt = 0; nt < 4; nt++)
#pragma unroll
        for (int mt = 0; mt < 4; mt++)
          acc[nt][mt] = __builtin_amdgcn_mfma_f32_16x16x32_bf16(
              af[nt], bx[mt], acc[nt][mt], 0, 0, 0);
    }
    __builtin_amdgcn_s_waitcnt(0);   // drains stage(kt+1): latency hidden
    __syncthreads();
  }

  const float* __restrict__ bias = z ? kbias : qbias;
  bf16* __restrict__ outp = z ? Kb : Qb;
#pragma unroll
  for (int nt = 0; nt < 4; nt++) {
    int n0 = w * 64 + nt * 16 + q * 4;          // D: n = quad*4 + reg
    float4 bv = *(const float4*)(bias + n0);
#pragma unroll
    for (int mt = 0; mt < 4; mt++) {
      int m = m0 + mt * 16 + m16;               // D: m = lane&15
      bf16x4 o = {(bf16)(acc[nt][mt][0] + bv.x), (bf16)(acc[nt][mt][1] + bv.y),
                  (bf16)(acc[nt][mt][2] + bv.z), (bf16)(acc[nt][mt][3] + bv.w)};
      *(bf16x4*)(outp + (size_t)m * NPROJ + n0) = o;
    }
  }
}

// ---------------- K2: scores (swapped, 2-phase) ----------------
// grid 512 (2/CU). Block: Q strip 128 rows in regs (all heads), K range 512
// as 8 sub-tiles of 64 rows, double-buffered 2x32KB LDS. MFMA A=K rows,
// B=Q rows -> D reg axis = k -> per-lane float4 nontemporal stores.
// kq = bx&7 matches XCD round-robin: each kq's 512KB K-slice stays L2-hot.
__global__ __launch_bounds__(256, 2) void k_scores(
    const bf16* __restrict__ Qb, const bf16* __restrict__ Kb,
    const float* __restrict__ iw, float* __restrict__ out) {
  __shared__ __align__(16) bf16 Ks[2][64 * 256];  // 2 x 32 KB
  const int t = threadIdx.x;
  const int lane = t & 63, w = t >> 6;
  const int m16 = lane & 15, q = lane >> 4;

  const int bx = blockIdx.x;
  const int kq = bx & 7;          // K range: kq*512 .. +511
  const int strip = bx >> 3;      // 0..63
  const int bz = strip >> 5;
  const int q0 = (strip & 31) * 128;
  const int k0 = kq * 512;

  const float whs[4] = {iw[0], iw[1], iw[2], iw[3]};

  // Q strip fragments (B operand) to registers, once per block
  bf16x8 aq[2][4][2];
  {
    const bf16* qp =
        Qb + (size_t)(bz * SEQ + q0 + w * 32 + m16) * NPROJ + q * 8;
#pragma unroll
    for (int qt = 0; qt < 2; qt++)
#pragma unroll
      for (int h = 0; h < 4; h++)
#pragma unroll
        for (int j = 0; j < 2; j++)
          aq[qt][h][j] = *(const bf16x8*)(qp + (size_t)qt * 16 * NPROJ +
                                          h * 64 + j * 32);
  }

  auto stage = [&](int buf, int st) {
    // 64 rows x 512B = 32 KB = 32 calls (8/wave), 2 rows/call
#pragma unroll
    for (int p = 0; p < 8; p++) {
      int g = w * 8 + p;
      int r = g * 2 + (lane >> 5);
      int c = (lane & 31) ^ (r & 31);           // XOR chunk swizzle
      async16(Kb + ((size_t)bz * SEQ + k0 + st * 64 + r) * NPROJ + c * 8,
              Ks[buf] + g * 512);
    }
  };

  stage(0, 0);
  __builtin_amdgcn_s_waitcnt(0);
  __syncthreads();

  for (int st = 0; st < 8; st++) {
    if (st < 7) stage((st + 1) & 1, st + 1);    // issue next sub-tile first
    const bf16* KsB = Ks[st & 1];

    f32x4 accf[4][2];
#pragma unroll
    for (int kt = 0; kt < 4; kt++)
#pragma unroll
      for (int qt = 0; qt < 2; qt++) accf[kt][qt] = {0.f, 0.f, 0.f, 0.f};

#pragma unroll
    for (int h = 0; h < 4; h++) {
      const float wh = whs[h];
      bf16x8 ak[4][2];
#pragma unroll
      for (int kt = 0; kt < 4; kt++) {
        int r = kt * 16 + m16;
        const bf16* kp = KsB + r * 256;
        int c0 = (h * 8 + q) ^ (r & 31);
        int c1 = (h * 8 + 4 + q) ^ (r & 31);
        ak[kt][0] = *(const bf16x8*)(kp + c0 * 8);
        ak[kt][1] = *(const bf16x8*)(kp + c1 * 8);
      }
#pragma unroll
      for (int kt = 0; kt < 4; kt++)
#pragma unroll
        for (int qt = 0; qt < 2; qt++) {
          f32x4 tacc = {0.f, 0.f, 0.f, 0.f};
          tacc = __builtin_amdgcn_mfma_f32_16x16x32_bf16(ak[kt][0],
                                                         aq[qt][h][0], tacc,
                                                         0, 0, 0);
          tacc = __builtin_amdgcn_mfma_f32_16x16x32_bf16(ak[kt][1],
                                                         aq[qt][h][1], tacc,
                                                         0, 0, 0);
#pragma unroll
          for (int e = 0; e < 4; e++)
            accf[kt][qt][e] += wh * fmaxf(tacc[e], 0.f);
        }
    }

    __builtin_amdgcn_s_waitcnt(0);  // drains stage(st+1): hidden under MFMA
    __syncthreads();

    // stores after the barrier: acks drain at end of NEXT phase (free slack)
#pragma unroll
    for (int qt = 0; qt < 2; qt++) {
      size_t rb = ((size_t)bz * SEQ + q0 + w * 32 + qt * 16 + m16) * SEQ;
#pragma unroll
      for (int kt = 0; kt < 4; kt++) {
        int col = k0 + st * 64 + kt * 16 + q * 4;   // D: k = quad*4 + reg
        __builtin_nontemporal_store(accf[kt][qt], (f32x4*)(out + rb + col));
      }
    }
  }
}

extern "C" void kernel_launch(void* const* d_in, const int* in_sizes, int n_in,
                              void* d_out, int out_size, void* d_ws, size_t ws_size,
                              hipStream_t stream) {
  const float* x  = (const float*)d_in[0];   // [2,4096,1024]
  const float* wq = (const float*)d_in[1];   // [256,1024]
  const float* qb = (const float*)d_in[2];   // [256]
  const float* wk = (const float*)d_in[3];   // [256,1024]
  const float* kb = (const float*)d_in[4];   // [256]
  const float* iw = (const float*)d_in[5];   // [4]
  float* out = (float*)d_out;                // [2,4096,4096] = 134 MB

  // workspace layout (9,437,184 B total, unchanged)
  char* ws = (char*)d_ws;
  bf16* wqb = (bf16*)ws;                               // 512 KB
  bf16* wkb = (bf16*)(ws + 524288);                    // 512 KB
  bf16* Qb  = (bf16*)(ws + 1048576);                   // 4 MB  [8192][256]
  bf16* Kb  = (bf16*)(ws + 1048576 + 4194304);         // 4 MB  [8192][256]
  // xb (16.8 MB) parked in d_out scratch: fully consumed by k_proj before
  // k_scores (stream-ordered) overwrites every byte of out.
  bf16* xb  = (bf16*)d_out;                            // [8192][1024] bf16

  k_convert<<<2176, 256, 0, stream>>>(x, wq, wk, xb, wqb, wkb);
  k_proj<<<dim3(128, 2), 256, 0, stream>>>(xb, wqb, wkb, qb, kb, Qb, Kb);
  k_scores<<<512, 256, 0, stream>>>(Qb, Kb, iw, out);
}

// Round 2
// 205.623 us; speedup vs baseline: 1.0309x; 1.0309x over previous
//
#include <hip/hip_runtime.h>

// LightningIndexer: out[b,q,k] = sum_h w_h * relu( (xWq^T+bq)[b,q,h,:] . (xWk^T+bk)[b,k,h,:] )
// B=2, S=4096, Dmodel=1024, H=4, HD=64.
// R6: counted-vmcnt pipeline (T3/T4) — raw s_barrier, NEVER vmcnt(0) in the
// main loops; stores issued after the 2nd barrier retire across the next
// phase. Nontemporal removed. Convert pass is weights-only; k_proj reads
// fp32 x with reg-staged convert (T14) at 2 blocks/CU.

typedef __bf16 bf16;
typedef __bf16 bf16x4 __attribute__((ext_vector_type(4)));
typedef __bf16 bf16x8 __attribute__((ext_vector_type(8)));
typedef float f32x4 __attribute__((ext_vector_type(4)));

#define SEQ 4096
#define DMODEL 1024
#define NPROJ 256       // NHEAD*HDIM
#define MTOT 8192       // NB*SEQ

// async global->LDS, 16B per lane; LDS dest = wave-uniform base + lane*16
__device__ __forceinline__ void async16(const void* g, void* l) {
  __builtin_amdgcn_global_load_lds(
      (const __attribute__((address_space(1))) void*)g,
      (__attribute__((address_space(3))) void*)l, 16, 0, 0);
}

// raw barrier with compiler fences so no memory op / ds_read is scheduled
// across it (rule #18 family: builtin s_barrier is not a compiler fence)
#define SBAR()                                   \
  do {                                           \
    asm volatile("" ::: "memory");               \
    __builtin_amdgcn_sched_barrier(0);           \
    __builtin_amdgcn_s_barrier();                \
    __builtin_amdgcn_sched_barrier(0);           \
    asm volatile("" ::: "memory");               \
  } while (0)

// ---------------- K0: convert Wq, Wk fp32 -> bf16 (2 MB total) ----------
__global__ __launch_bounds__(256) void k_convert(const float* __restrict__ wq,
                                                 const float* __restrict__ wk,
                                                 bf16* __restrict__ wqb,
                                                 bf16* __restrict__ wkb) {
  int i = blockIdx.x * 256 + threadIdx.x;  // 65536 float4 groups per matrix
  float4 a = ((const float4*)wq)[i];
  bf16x4 oa = {(bf16)a.x, (bf16)a.y, (bf16)a.z, (bf16)a.w};
  ((bf16x4*)wqb)[i] = oa;
  float4 b = ((const float4*)wk)[i];
  bf16x4 ob = {(bf16)b.x, (bf16)b.y, (bf16)b.z, (bf16)b.w};
  ((bf16x4*)wkb)[i] = ob;
}

// ---------------- K1: projection GEMM (swapped MFMA, counted pipeline) ---
// out[m,n] = sum_d x[m,d]*W[n,d] + bias[n], bf16 out.
// BM=64, BN=128, BK=64. grid (128 mtiles, 2 z, 2 nh) = 512 blocks, 2/CU.
// A (x fp32) reg-staged: 4 dwordx4 loads -> cvt -> 2 swizzled ds_write_b128.
// B (W bf16) via async16. Per-iter VMEM ledger: [xload 4][asyncB 4];
// wait vmcnt(8) drains asyncB(t); wait vmcnt(4) drains xload(t+1).
__global__ __launch_bounds__(256, 2) void k_proj(
    const float* __restrict__ x, const bf16* __restrict__ wqb,
    const bf16* __restrict__ wkb, const float* __restrict__ qbias,
    const float* __restrict__ kbias, bf16* __restrict__ Qb,
    bf16* __restrict__ Kb) {
  __shared__ __align__(16) bf16 As[2][64 * 64];    // 8 KB each
  __shared__ __align__(16) bf16 Bs[2][128 * 64];   // 16 KB each (48 KB total)
  const int t = threadIdx.x;
  const int lane = t & 63, w = t >> 6;
  const int m16 = lane & 15, q = lane >> 4;
  const int m0 = blockIdx.x * 64;
  const int z = blockIdx.y;                        // 0 = Q, 1 = K
  const int nh = blockIdx.z;                       // n half
  const bf16* __restrict__ W = z ? wkb : wqb;

  // A staging: lane owns row ar, fp32 cols ac..ac+15 of the 64-wide K-slice
  const int ar = w * 16 + (lane >> 2);
  const int ac = (lane & 3) * 16;
  const float* __restrict__ xrow = x + (size_t)(m0 + ar) * DMODEL + ac;

  f32x4 acc[2][4];
#pragma unroll
  for (int nt = 0; nt < 2; nt++)
#pragma unroll
    for (int mt = 0; mt < 4; mt++) acc[nt][mt] = {0.f, 0.f, 0.f, 0.f};

  float4 xv[4];
  auto xload = [&](int kt) {
#pragma unroll
    for (int i = 0; i < 4; i++)
      xv[i] = *(const float4*)(xrow + kt * 64 + i * 4);
  };
  auto stageB = [&](int buf, int kt) {
#pragma unroll
    for (int p = 0; p < 4; p++) {
      int g = w * 4 + p;                 // 8-row group, wave-uniform base
      int r = g * 8 + (lane >> 3);
      int c = (lane & 7) ^ (r & 7);      // XOR chunk swizzle (source side)
      async16(W + (size_t)(nh * 128 + r) * DMODEL + kt * 64 + c * 8,
              Bs[buf] + g * 512);
    }
  };
  auto writeA = [&](int buf) {
    bf16x8 o0 = {(bf16)xv[0].x, (bf16)xv[0].y, (bf16)xv[0].z, (bf16)xv[0].w,
                 (bf16)xv[1].x, (bf16)xv[1].y, (bf16)xv[1].z, (bf16)xv[1].w};
    bf16x8 o1 = {(bf16)xv[2].x, (bf16)xv[2].y, (bf16)xv[2].z, (bf16)xv[2].w,
                 (bf16)xv[3].x, (bf16)xv[3].y, (bf16)xv[3].z, (bf16)xv[3].w};
    int k0 = (lane & 3) * 2;             // logical 8-elem chunk index
    *(bf16x8*)(As[buf] + ar * 64 + ((k0) ^ (ar & 7)) * 8) = o0;
    *(bf16x8*)(As[buf] + ar * 64 + ((k0 + 1) ^ (ar & 7)) * 8) = o1;
  };
  auto compute = [&](int buf) {
    const bf16* As_ = As[buf];
    const bf16* Bs_ = Bs[buf];
#pragma unroll
    for (int s = 0; s < 2; s++) {
      bf16x8 af[2], bxr[4];
#pragma unroll
      for (int nt = 0; nt < 2; nt++) {
        int n = w * 32 + nt * 16 + m16;
        int cc = (s * 4 + q) ^ (n & 7);
        af[nt] = *(const bf16x8*)(Bs_ + n * 64 + cc * 8);
      }
#pragma unroll
      for (int mt = 0; mt < 4; mt++) {
        int m = mt * 16 + m16;
        int cc = (s * 4 + q) ^ (m & 7);
        bxr[mt] = *(const bf16x8*)(As_ + m * 64 + cc * 8);
      }
#pragma unroll
      for (int nt = 0; nt < 2; nt++)
#pragma unroll
        for (int mt = 0; mt < 4; mt++)
          acc[nt][mt] = __builtin_amdgcn_mfma_f32_16x16x32_bf16(
              af[nt], bxr[mt], acc[nt][mt], 0, 0, 0);
    }
  };

  // prologue: tile 0
  xload(0);
  stageB(0, 0);
  asm volatile("s_waitcnt vmcnt(4)" ::: "memory");  // xload(0) done
  writeA(0);

  for (int kt = 0; kt < 15; kt++) {
    xload(kt + 1);
    stageB((kt + 1) & 1, kt + 1);
    // drains asyncB(kt) [+ leaves xload/asyncB(kt+1) in flight]; ds_writes
    // of As(kt) visible to all waves after the barrier
    asm volatile("s_waitcnt vmcnt(8) lgkmcnt(0)" ::: "memory");
    SBAR();
    compute(kt & 1);
    asm volatile("s_waitcnt vmcnt(4)" ::: "memory");  // xload(kt+1) done
    writeA((kt + 1) & 1);
    SBAR();  // all waves done reading buf (kt&1) before next stage hits it
  }
  // peeled last iteration (no stage): full drain is cheap once
  asm volatile("s_waitcnt vmcnt(0) lgkmcnt(0)" ::: "memory");
  SBAR();
  compute(1);

  const float* __restrict__ bias = z ? kbias : qbias;
  bf16* __restrict__ outp = z ? Kb : Qb;
#pragma unroll
  for (int nt = 0; nt < 2; nt++) {
    int ncol = nh * 128 + w * 32 + nt * 16 + q * 4;  // D reg axis = n
    float4 bv = *(const float4*)(bias + ncol);
#pragma unroll
    for (int mt = 0; mt < 4; mt++) {
      int m = m0 + mt * 16 + m16;                    // D: m = lane&15
      bf16x4 o = {(bf16)(acc[nt][mt][0] + bv.x), (bf16)(acc[nt][mt][1] + bv.y),
                  (bf16)(acc[nt][mt][2] + bv.z), (bf16)(acc[nt][mt][3] + bv.w)};
      *(bf16x4*)(outp + (size_t)m * NPROJ + ncol) = o;
    }
  }
}

// ---------------- K2: scores (swapped MFMA, counted pipeline) ------------
// grid 512 (2/CU). Q strip 128 rows in regs; K range 512 rows as 8 subtiles
// of 64 rows, dbuf 2x32KB. Per-iter VMEM ledger: [STAGE(t+1) 8 loads] ...
// [stores(t) 8]; wait vmcnt(8) drains STAGE(t)+stores(t-1), leaves
// STAGE(t+1) flying -> stores retire across a full phase, never on the
// critical path. kq = bx&7 pins each 512-row K slice to one XCD's L2.
__global__ __launch_bounds__(256, 2) void k_scores(
    const bf16* __restrict__ Qb, const bf16* __restrict__ Kb,
    const float* __restrict__ iw, float* __restrict__ out) {
  __shared__ __align__(16) bf16 Ks[2][64 * 256];  // 2 x 32 KB
  const int t = threadIdx.x;
  const int lane = t & 63, w = t >> 6;
  const int m16 = lane & 15, q = lane >> 4;

  const int bx = blockIdx.x;
  const int kq = bx & 7;          // K range: kq*512 .. +511
  const int strip = bx >> 3;      // 0..63
  const int bz = strip >> 5;
  const int q0 = (strip & 31) * 128;
  const int k0 = kq * 512;

  const float whs[4] = {iw[0], iw[1], iw[2], iw[3]};

  // Q strip fragments (MFMA B operand) to registers, once per block
  bf16x8 aq[2][4][2];
  {
    const bf16* qp =
        Qb + (size_t)(bz * SEQ + q0 + w * 32 + m16) * NPROJ + q * 8;
#pragma unroll
    for (int qt = 0; qt < 2; qt++)
#pragma unroll
      for (int h = 0; h < 4; h++)
#pragma unroll
        for (int j = 0; j < 2; j++)
          aq[qt][h][j] = *(const bf16x8*)(qp + (size_t)qt * 16 * NPROJ +
                                          h * 64 + j * 32);
  }

  auto stage = [&](int buf, int st) {
    // 64 rows x 512B = 32 KB = 32 calls (8/wave), 2 rows/call
#pragma unroll
    for (int p = 0; p < 8; p++) {
      int g = w * 8 + p;
      int r = g * 2 + (lane >> 5);
      int c = (lane & 31) ^ (r & 31);           // XOR chunk swizzle
      async16(Kb + ((size_t)bz * SEQ + k0 + st * 64 + r) * NPROJ + c * 8,
              Ks[buf] + g * 512);
    }
  };

  // prologue: subtile 0 staged and drained once
  stage(0, 0);
  asm volatile("s_waitcnt vmcnt(0)" ::: "memory");
  SBAR();

  for (int st = 0; st < 8; st++) {
    if (st < 7) stage((st + 1) & 1, st + 1);
    // outstanding: STAGE(st)[8] + stores(st-1)[8] + STAGE(st+1)[8];
    // vmcnt(8) drains the oldest 16 -> STAGE(st) landed, old stores retired
    asm volatile("s_waitcnt vmcnt(8)" ::: "memory");
    SBAR();

    const bf16* KsB = Ks[st & 1];
    f32x4 accf[4][2];
#pragma unroll
    for (int kt = 0; kt < 4; kt++)
#pragma unroll
      for (int qt = 0; qt < 2; qt++) accf[kt][qt] = {0.f, 0.f, 0.f, 0.f};

#pragma unroll
    for (int h = 0; h < 4; h++) {
      const float wh = whs[h];
      bf16x8 ak[4][2];
#pragma unroll
      for (int kt = 0; kt < 4; kt++) {
        int r = kt * 16 + m16;
        const bf16* kp = KsB + r * 256;
        int c0 = (h * 8 + q) ^ (r & 31);
        int c1 = (h * 8 + 4 + q) ^ (r & 31);
        ak[kt][0] = *(const bf16x8*)(kp + c0 * 8);
        ak[kt][1] = *(const bf16x8*)(kp + c1 * 8);
      }
#pragma unroll
      for (int kt = 0; kt < 4; kt++)
#pragma unroll
        for (int qt = 0; qt < 2; qt++) {
          f32x4 tacc = {0.f, 0.f, 0.f, 0.f};
          tacc = __builtin_amdgcn_mfma_f32_16x16x32_bf16(ak[kt][0],
                                                         aq[qt][h][0], tacc,
                                                         0, 0, 0);
          tacc = __builtin_amdgcn_mfma_f32_16x16x32_bf16(ak[kt][1],
                                                         aq[qt][h][1], tacc,
                                                         0, 0, 0);
#pragma unroll
          for (int e = 0; e < 4; e++)
            accf[kt][qt][e] += wh * fmaxf(tacc[e], 0.f);
        }
    }

    SBAR();  // all waves done reading buf (st&1) before next stage hits it

    // stores after the barrier: register-only inputs, retire across the
    // next phase (drained by vmcnt(8) one iteration later, never to 0)
#pragma unroll
    for (int qt = 0; qt < 2; qt++) {
      size_t rb = ((size_t)bz * SEQ + q0 + w * 32 + qt * 16 + m16) * SEQ;
#pragma unroll
      for (int kt = 0; kt < 4; kt++) {
        int col = k0 + st * 64 + kt * 16 + q * 4;   // D reg axis = k
        *(f32x4*)(out + rb + col) = accf[kt][qt];
      }
    }
  }
}

extern "C" void kernel_launch(void* const* d_in, const int* in_sizes, int n_in,
                              void* d_out, int out_size, void* d_ws, size_t ws_size,
                              hipStream_t stream) {
  const float* x  = (const float*)d_in[0];   // [2,4096,1024]
  const float* wq = (const float*)d_in[1];   // [256,1024]
  const float* qb = (const float*)d_in[2];   // [256]
  const float* wk = (const float*)d_in[3];   // [256,1024]
  const float* kb = (const float*)d_in[4];   // [256]
  const float* iw = (const float*)d_in[5];   // [4]
  float* out = (float*)d_out;                // [2,4096,4096]

  // workspace layout (9,437,184 B total)
  char* ws = (char*)d_ws;
  bf16* wqb = (bf16*)ws;                               // 512 KB
  bf16* wkb = (bf16*)(ws + 524288);                    // 512 KB
  bf16* Qb  = (bf16*)(ws + 1048576);                   // 4 MB  [8192][256]
  bf16* Kb  = (bf16*)(ws + 1048576 + 4194304);         // 4 MB  [8192][256]

  k_convert<<<256, 256, 0, stream>>>(wq, wk, wqb, wkb);
  k_proj<<<dim3(128, 2, 2), 256, 0, stream>>>(x, wqb, wkb, qb, kb, Qb, Kb);
  k_scores<<<512, 256, 0, stream>>>(Qb, Kb, iw, out);
}